// Round 1
// baseline (325.605 us; speedup 1.0000x reference)
//
#include <hip/hip_runtime.h>
#include <hip/hip_bf16.h>

// ---------------------------------------------------------------------------
// DeformableSpatialEncoder on MI355X (gfx950)
//
// Pipeline (N=64 images, Lq=196 tokens, D=768, heads=4, Dh=192, points=4):
//   1. prep:    cast embed_w -> bf16 [768,768]; build Wcat bf16 [896,768]
//               (= concat(value_w, off_w, aw_w, zero-pad)); bcat; zero core_mean
//   2. im2col:  x (64,3,224,224) f32 -> A bf16 [12544, 768]  (k = c*256+p*16+q)
//   3. gemm1:   feat_bf16 [12544,768] = A @ Wemb^T + embed_b
//   4. gemm2:   catout f32 [12544,896] = feat @ Wcat^T + bcat
//               cols 0..767 value | 768..799 off | 800..815 aw-logits
//   5. deform:  core_mean[64,768] += mean_lq( softmax(aw) * bilinear(value) )
//   6. pooled = core_mean @ outp_w^T + outp_b     (mean commutes with linear!)
//   7. final  = pooled @ proj_w^T + proj_b -> d_out
// ---------------------------------------------------------------------------

using bf16 = __bf16;
typedef bf16  bf16x8 __attribute__((ext_vector_type(8)));
typedef float f32x4  __attribute__((ext_vector_type(4)));

#define N_IMG   64
#define LQ      196
#define DM      768
#define NH      4
#define DH      192
#define NPT     4
#define M_ROWS  (N_IMG * LQ)        // 12544
#define NCAT    896                 // 768 value + 32 off + 16 aw + 80 pad

// ---- workspace layout (bytes, all 256-aligned) ----
#define OFF_A     ((size_t)0)                      // 12544*768*2 = 19267584
#define OFF_FEAT  (OFF_A    + 19267584)            // 19267584
#define OFF_WEMB  (OFF_FEAT + 19267584)            // 768*768*2   = 1179648
#define OFF_WCAT  (OFF_WEMB + 1179648)             // 896*768*2   = 1376256
#define OFF_BCAT  (OFF_WCAT + 1376256)             // 4096
#define OFF_CATO  (OFF_BCAT + 4096)                // 12544*896*4 = 44957696
#define OFF_CORE  (OFF_CATO + 44957696)            // 196608
#define OFF_POOL  (OFF_CORE + 196608)              // 196608

__device__ __forceinline__ void gload_lds16(const bf16* g, bf16* l) {
#if __has_builtin(__builtin_amdgcn_global_load_lds)
  __builtin_amdgcn_global_load_lds(
      (const __attribute__((address_space(1))) void*)g,
      (__attribute__((address_space(3))) void*)l, 16, 0, 0);
#else
  // fallback: manual copy (8 bf16 = 16B)
  *(bf16x8*)l = *(const bf16x8*)g;
#endif
}

// ---------------------------------------------------------------------------
// prep: weight casts/concat + bias concat + core_mean zero-init
// grid 2688 x 256  (covers 896*768 = 688128)
// ---------------------------------------------------------------------------
__global__ void prep_kernel(const float* __restrict__ embed_w,
                            const float* __restrict__ value_w,
                            const float* __restrict__ off_w,
                            const float* __restrict__ aw_w,
                            const float* __restrict__ value_b,
                            const float* __restrict__ off_b,
                            const float* __restrict__ aw_b,
                            bf16* __restrict__ Wemb, bf16* __restrict__ Wcat,
                            float* __restrict__ bcat, float* __restrict__ core) {
  int idx = blockIdx.x * 256 + threadIdx.x;
  if (idx < DM * DM) Wemb[idx] = (bf16)embed_w[idx];
  if (idx < NCAT * DM) {
    int r = idx / DM, k = idx - r * DM;
    float v = 0.f;
    if (r < 768)       v = value_w[idx];
    else if (r < 800)  v = off_w[(r - 768) * DM + k];
    else if (r < 816)  v = aw_w[(r - 800) * DM + k];
    Wcat[idx] = (bf16)v;
  }
  if (idx < NCAT) {
    float v = 0.f;
    if (idx < 768)      v = value_b[idx];
    else if (idx < 800) v = off_b[idx - 768];
    else if (idx < 816) v = aw_b[idx - 800];
    bcat[idx] = v;
  }
  if (idx < N_IMG * DM) core[idx] = 0.f;
}

// ---------------------------------------------------------------------------
// im2col: x[n][c][y][:] -> A[n*196 + (y/16)*14 + w][c*256 + (y%16)*16 + q]
// thread t = ((n*3+c)*224 + y)*14 + w handles 16 contiguous q's.
// grid 2352 x 256 (64*3*224*14 = 602112 threads)
// ---------------------------------------------------------------------------
__global__ void im2col_kernel(const float* __restrict__ x, bf16* __restrict__ A) {
  int t = blockIdx.x * 256 + threadIdx.x;
  if (t >= N_IMG * 3 * 224 * 14) return;
  int w    = t % 14;
  int rest = t / 14;            // (n*3+c)*224 + y
  int y    = rest % 224;
  int nc   = rest / 224;        // n*3 + c
  int c    = nc % 3;
  int n    = nc / 3;
  int h = y >> 4, p = y & 15;
  const float* src = x + (size_t)rest * 224 + w * 16;
  bf16* dst = A + (size_t)(n * LQ + h * 14 + w) * DM + c * 256 + p * 16;
#pragma unroll
  for (int q = 0; q < 16; q += 4) {
    float4 v = *(const float4*)(src + q);
    dst[q + 0] = (bf16)v.x; dst[q + 1] = (bf16)v.y;
    dst[q + 2] = (bf16)v.z; dst[q + 3] = (bf16)v.w;
  }
}

// ---------------------------------------------------------------------------
// gemm_bt: C[M,N] = A[M,K]bf16 @ B[N,K]bf16 ^T + bias[N]
// 128x128 tile, BK=64, 256 threads (4 waves, 2x2), mfma_f32_16x16x32_bf16.
// M % 128 == 0, N % 128 == 0, K % 64 == 0 (guaranteed by padding).
// ---------------------------------------------------------------------------
template <typename OutT>
__global__ void gemm_bt(const bf16* __restrict__ A, const bf16* __restrict__ B,
                        const float* __restrict__ bias, OutT* __restrict__ C,
                        int M, int N, int K) {
  __shared__ bf16 As[128 * 64];
  __shared__ bf16 Bs[128 * 64];

  const int tid  = threadIdx.x;
  const int wave = tid >> 6;
  const int lane = tid & 63;
  const int mBase = blockIdx.x * 128;
  const int nBase = blockIdx.y * 128;
  const int wm = wave & 1;        // wave row (0..1)
  const int wn = wave >> 1;       // wave col (0..1)
  const int quad = lane >> 4;     // 0..3
  const int r16  = lane & 15;

  const f32x4 zero = {0.f, 0.f, 0.f, 0.f};
  f32x4 acc[4][4];
#pragma unroll
  for (int mi = 0; mi < 4; ++mi)
#pragma unroll
    for (int ni = 0; ni < 4; ++ni) acc[mi][ni] = zero;

  // staging: wave w fills rows [w*32, w*32+32); each global_load_lds moves
  // 8 rows (64 lanes x 16B). lane L: row += L>>3, col = (L&7)*8.
  const int srow = wave * 32 + (lane >> 3);
  const int scol = (lane & 7) * 8;
  const bf16* Ag = A + (size_t)(mBase + srow) * K + scol;
  const bf16* Bg = B + (size_t)(nBase + srow) * K + scol;
  bf16* Al = As + srow * 64 + scol;
  bf16* Bl = Bs + srow * 64 + scol;

  for (int kt = 0; kt < K; kt += 64) {
#pragma unroll
    for (int i = 0; i < 4; ++i) {
      gload_lds16(Ag + (size_t)(i * 8) * K + kt, Al + i * 8 * 64);
      gload_lds16(Bg + (size_t)(i * 8) * K + kt, Bl + i * 8 * 64);
    }
    __syncthreads();
#pragma unroll
    for (int kk = 0; kk < 64; kk += 32) {
      bf16x8 af[4], bfr[4];
#pragma unroll
      for (int mi = 0; mi < 4; ++mi)
        af[mi] = *(const bf16x8*)&As[(wm * 64 + mi * 16 + r16) * 64 + kk + quad * 8];
#pragma unroll
      for (int ni = 0; ni < 4; ++ni)
        bfr[ni] = *(const bf16x8*)&Bs[(wn * 64 + ni * 16 + r16) * 64 + kk + quad * 8];
#pragma unroll
      for (int mi = 0; mi < 4; ++mi)
#pragma unroll
        for (int ni = 0; ni < 4; ++ni)
          acc[mi][ni] = __builtin_amdgcn_mfma_f32_16x16x32_bf16(
              af[mi], bfr[ni], acc[mi][ni], 0, 0, 0);
    }
    __syncthreads();
  }

  // epilogue: C row = quad*4 + reg, col = lane&15 (m89/m91-verified layout)
#pragma unroll
  for (int ni = 0; ni < 4; ++ni) {
    const int col = nBase + wn * 64 + ni * 16 + r16;
    const float bv = bias[col];
#pragma unroll
    for (int mi = 0; mi < 4; ++mi) {
      const int row0 = mBase + wm * 64 + mi * 16 + quad * 4;
#pragma unroll
      for (int rr = 0; rr < 4; ++rr) {
        float v = acc[mi][ni][rr] + bv;
        C[(size_t)(row0 + rr) * N + col] = (OutT)v;
      }
    }
  }
}

// ---------------------------------------------------------------------------
// deform: grid (64, 4, 7), block 192 (one channel per thread).
// Block (n, m, s) handles lq in [s*28, s*28+28); accumulates into
// core[n*768 + m*192 + dh] via atomicAdd (7 partials per address).
// ---------------------------------------------------------------------------
__global__ void deform_kernel(const float* __restrict__ catout,
                              float* __restrict__ core) {
  const int n  = blockIdx.x;
  const int m  = blockIdx.y;
  const int s  = blockIdx.z;
  const int dh = threadIdx.x;  // 0..191
  const float* base  = catout + (size_t)n * LQ * NCAT;
  const float* vbase = base + m * DH;

  float acc = 0.f;
  const int lq0 = s * 28;
  for (int lq = lq0; lq < lq0 + 28; ++lq) {
    const float* row = base + (size_t)lq * NCAT;
    // softmax over the 4 points (uniform across threads; broadcast loads)
    const float l0 = row[800 + m * 4 + 0];
    const float l1 = row[800 + m * 4 + 1];
    const float l2 = row[800 + m * 4 + 2];
    const float l3 = row[800 + m * 4 + 3];
    const float mx = fmaxf(fmaxf(l0, l1), fmaxf(l2, l3));
    const float e0 = __expf(l0 - mx), e1 = __expf(l1 - mx);
    const float e2 = __expf(l2 - mx), e3 = __expf(l3 - mx);
    const float inv = 1.f / (e0 + e1 + e2 + e3);
    const float ew[4] = {e0 * inv, e1 * inv, e2 * inv, e3 * inv};

    const int h = lq / 14, w = lq - (lq / 14) * 14;
    // px = ref_x*14 + off_x - 0.5, ref_x = w/13 (linspace(0,1,14))
    const float px0 = (float)w * (14.f / 13.f) - 0.5f;
    const float py0 = (float)h * (14.f / 13.f) - 0.5f;
#pragma unroll
    for (int p = 0; p < 4; ++p) {
      const float offx = row[768 + (m * 4 + p) * 2 + 0];
      const float offy = row[768 + (m * 4 + p) * 2 + 1];
      const float px = px0 + offx;
      const float py = py0 + offy;
      const float fx = floorf(px), fy = floorf(py);
      const int x0 = (int)fx, y0 = (int)fy;
      const float wx1 = px - fx, wy1 = py - fy;
      const float wx0 = 1.f - wx1, wy0 = 1.f - wy1;
      float sv = 0.f;
      if (y0 >= 0 && y0 < 14) {
        const float* r0 = vbase + (size_t)(y0 * 14) * NCAT;
        if (x0 >= 0 && x0 < 14)         sv += wx0 * wy0 * r0[(size_t)x0 * NCAT + dh];
        if (x0 + 1 >= 0 && x0 + 1 < 14) sv += wx1 * wy0 * r0[(size_t)(x0 + 1) * NCAT + dh];
      }
      if (y0 + 1 >= 0 && y0 + 1 < 14) {
        const float* r1 = vbase + (size_t)((y0 + 1) * 14) * NCAT;
        if (x0 >= 0 && x0 < 14)         sv += wx0 * wy1 * r1[(size_t)x0 * NCAT + dh];
        if (x0 + 1 >= 0 && x0 + 1 < 14) sv += wx1 * wy1 * r1[(size_t)(x0 + 1) * NCAT + dh];
      }
      acc += ew[p] * sv;
    }
  }
  atomicAdd(&core[(size_t)n * DM + m * DH + dh], acc * (1.f / 196.f));
}

// ---------------------------------------------------------------------------
// small_linear: out[n][d] = sum_k in[n][k] * W[d][k] + b[d]
// grid (64, 3), block 256. W rows L2-cached (2.4 MB).
// ---------------------------------------------------------------------------
__global__ void small_linear(const float* __restrict__ in,
                             const float* __restrict__ W,
                             const float* __restrict__ b,
                             float* __restrict__ out) {
  const int n = blockIdx.x;
  const int d = blockIdx.y * 256 + threadIdx.x;
  const float4* a4 = (const float4*)(in + (size_t)n * DM);
  const float4* w4 = (const float4*)(W + (size_t)d * DM);
  float acc = 0.f;
#pragma unroll 4
  for (int k = 0; k < DM / 4; ++k) {
    float4 a = a4[k], w = w4[k];
    acc += a.x * w.x + a.y * w.y + a.z * w.z + a.w * w.w;
  }
  out[(size_t)n * DM + d] = acc + b[d];
}

// ---------------------------------------------------------------------------
extern "C" void kernel_launch(void* const* d_in, const int* in_sizes, int n_in,
                              void* d_out, int out_size, void* d_ws, size_t ws_size,
                              hipStream_t stream) {
  const float* x       = (const float*)d_in[0];
  const float* embed_w = (const float*)d_in[1];
  const float* embed_b = (const float*)d_in[2];
  const float* value_w = (const float*)d_in[3];
  const float* value_b = (const float*)d_in[4];
  const float* off_w   = (const float*)d_in[5];
  const float* off_b   = (const float*)d_in[6];
  const float* aw_w    = (const float*)d_in[7];
  const float* aw_b    = (const float*)d_in[8];
  const float* outp_w  = (const float*)d_in[9];
  const float* outp_b  = (const float*)d_in[10];
  const float* proj_w  = (const float*)d_in[11];
  const float* proj_b  = (const float*)d_in[12];
  float* out = (float*)d_out;

  char* ws = (char*)d_ws;
  bf16*  A      = (bf16*)(ws + OFF_A);
  bf16*  feat   = (bf16*)(ws + OFF_FEAT);
  bf16*  Wemb   = (bf16*)(ws + OFF_WEMB);
  bf16*  Wcat   = (bf16*)(ws + OFF_WCAT);
  float* bcat   = (float*)(ws + OFF_BCAT);
  float* catout = (float*)(ws + OFF_CATO);
  float* core   = (float*)(ws + OFF_CORE);
  float* pooled = (float*)(ws + OFF_POOL);

  prep_kernel<<<dim3(2688), dim3(256), 0, stream>>>(
      embed_w, value_w, off_w, aw_w, value_b, off_b, aw_b, Wemb, Wcat, bcat, core);

  im2col_kernel<<<dim3(2352), dim3(256), 0, stream>>>(x, A);

  gemm_bt<bf16><<<dim3(M_ROWS / 128, DM / 128), dim3(256), 0, stream>>>(
      A, Wemb, embed_b, feat, M_ROWS, DM, DM);

  gemm_bt<float><<<dim3(M_ROWS / 128, NCAT / 128), dim3(256), 0, stream>>>(
      feat, Wcat, bcat, catout, M_ROWS, NCAT, DM);

  deform_kernel<<<dim3(N_IMG, NH, 7), dim3(192), 0, stream>>>(catout, core);

  small_linear<<<dim3(N_IMG, 3), dim3(256), 0, stream>>>(core, outp_w, outp_b, pooled);
  small_linear<<<dim3(N_IMG, 3), dim3(256), 0, stream>>>(pooled, proj_w, proj_b, out);
}

// Round 2
// 312.119 us; speedup vs baseline: 1.0432x; 1.0432x over previous
//
#include <hip/hip_runtime.h>
#include <hip/hip_bf16.h>

// ---------------------------------------------------------------------------
// DeformableSpatialEncoder on MI355X (gfx950)
//
// Pipeline (N=64 images, Lq=196 tokens, D=768, heads=4, Dh=192, points=4):
//   1. prep:    cast embed_w -> bf16 [768,768]; build Wcat bf16 [896,768]
//               (= concat(value_w, off_w, aw_w, zero-pad)); bcat; zero core_mean
//   2. im2col:  x (64,3,224,224) f32 -> A bf16 [12544, 768]  (k = c*256+p*16+q)
//   3. gemm1:   feat_bf16 [12544,768] = A @ Wemb^T + embed_b
//   4. gemm2:   catout f32 [12544,896] = feat @ Wcat^T + bcat
//               cols 0..767 value | 768..799 off | 800..815 aw-logits
//   5. deform:  core_mean[64,768] += mean_lq( softmax(aw) * bilinear(value) )
//               R1: latency-bound fix — block=(n, lq-group-of-4, ch-third),
//               thread=channel, 37.6k waves (was 5376), 4 unrolled lq chains.
//   6. pooled = core_mean @ outp_w^T + outp_b     (mean commutes with linear!)
//   7. final  = pooled @ proj_w^T + proj_b -> d_out
// ---------------------------------------------------------------------------

using bf16 = __bf16;
typedef bf16  bf16x8 __attribute__((ext_vector_type(8)));
typedef float f32x4  __attribute__((ext_vector_type(4)));

#define N_IMG   64
#define LQ      196
#define DM      768
#define NH      4
#define DH      192
#define NPT     4
#define M_ROWS  (N_IMG * LQ)        // 12544
#define NCAT    896                 // 768 value + 32 off + 16 aw + 80 pad

// ---- workspace layout (bytes, all 256-aligned) ----
#define OFF_A     ((size_t)0)                      // 12544*768*2 = 19267584
#define OFF_FEAT  (OFF_A    + 19267584)            // 19267584
#define OFF_WEMB  (OFF_FEAT + 19267584)            // 768*768*2   = 1179648
#define OFF_WCAT  (OFF_WEMB + 1179648)             // 896*768*2   = 1376256
#define OFF_BCAT  (OFF_WCAT + 1376256)             // 4096
#define OFF_CATO  (OFF_BCAT + 4096)                // 12544*896*4 = 44957696
#define OFF_CORE  (OFF_CATO + 44957696)            // 196608
#define OFF_POOL  (OFF_CORE + 196608)              // 196608

__device__ __forceinline__ void gload_lds16(const bf16* g, bf16* l) {
#if __has_builtin(__builtin_amdgcn_global_load_lds)
  __builtin_amdgcn_global_load_lds(
      (const __attribute__((address_space(1))) void*)g,
      (__attribute__((address_space(3))) void*)l, 16, 0, 0);
#else
  *(bf16x8*)l = *(const bf16x8*)g;
#endif
}

// ---------------------------------------------------------------------------
// prep: weight casts/concat + bias concat + core_mean zero-init
// grid 2688 x 256  (covers 896*768 = 688128)
// ---------------------------------------------------------------------------
__global__ void prep_kernel(const float* __restrict__ embed_w,
                            const float* __restrict__ value_w,
                            const float* __restrict__ off_w,
                            const float* __restrict__ aw_w,
                            const float* __restrict__ value_b,
                            const float* __restrict__ off_b,
                            const float* __restrict__ aw_b,
                            bf16* __restrict__ Wemb, bf16* __restrict__ Wcat,
                            float* __restrict__ bcat, float* __restrict__ core) {
  int idx = blockIdx.x * 256 + threadIdx.x;
  if (idx < DM * DM) Wemb[idx] = (bf16)embed_w[idx];
  if (idx < NCAT * DM) {
    int r = idx / DM, k = idx - r * DM;
    float v = 0.f;
    if (r < 768)       v = value_w[idx];
    else if (r < 800)  v = off_w[(r - 768) * DM + k];
    else if (r < 816)  v = aw_w[(r - 800) * DM + k];
    Wcat[idx] = (bf16)v;
  }
  if (idx < NCAT) {
    float v = 0.f;
    if (idx < 768)      v = value_b[idx];
    else if (idx < 800) v = off_b[idx - 768];
    else if (idx < 816) v = aw_b[idx - 800];
    bcat[idx] = v;
  }
  if (idx < N_IMG * DM) core[idx] = 0.f;
}

// ---------------------------------------------------------------------------
// im2col: x[n][c][y][:] -> A[n*196 + (y/16)*14 + w][c*256 + (y%16)*16 + q]
// ---------------------------------------------------------------------------
__global__ void im2col_kernel(const float* __restrict__ x, bf16* __restrict__ A) {
  int t = blockIdx.x * 256 + threadIdx.x;
  if (t >= N_IMG * 3 * 224 * 14) return;
  int w    = t % 14;
  int rest = t / 14;            // (n*3+c)*224 + y
  int y    = rest % 224;
  int nc   = rest / 224;        // n*3 + c
  int c    = nc % 3;
  int n    = nc / 3;
  int h = y >> 4, p = y & 15;
  const float* src = x + (size_t)rest * 224 + w * 16;
  bf16* dst = A + (size_t)(n * LQ + h * 14 + w) * DM + c * 256 + p * 16;
#pragma unroll
  for (int q = 0; q < 16; q += 4) {
    float4 v = *(const float4*)(src + q);
    dst[q + 0] = (bf16)v.x; dst[q + 1] = (bf16)v.y;
    dst[q + 2] = (bf16)v.z; dst[q + 3] = (bf16)v.w;
  }
}

// ---------------------------------------------------------------------------
// gemm_bt: C[M,N] = A[M,K]bf16 @ B[N,K]bf16 ^T + bias[N]
// 128x128 tile, BK=64, 256 threads (4 waves, 2x2), mfma_f32_16x16x32_bf16.
// ---------------------------------------------------------------------------
template <typename OutT>
__global__ void gemm_bt(const bf16* __restrict__ A, const bf16* __restrict__ B,
                        const float* __restrict__ bias, OutT* __restrict__ C,
                        int M, int N, int K) {
  __shared__ bf16 As[128 * 64];
  __shared__ bf16 Bs[128 * 64];

  const int tid  = threadIdx.x;
  const int wave = tid >> 6;
  const int lane = tid & 63;
  const int mBase = blockIdx.x * 128;
  const int nBase = blockIdx.y * 128;
  const int wm = wave & 1;        // wave row (0..1)
  const int wn = wave >> 1;       // wave col (0..1)
  const int quad = lane >> 4;     // 0..3
  const int r16  = lane & 15;

  const f32x4 zero = {0.f, 0.f, 0.f, 0.f};
  f32x4 acc[4][4];
#pragma unroll
  for (int mi = 0; mi < 4; ++mi)
#pragma unroll
    for (int ni = 0; ni < 4; ++ni) acc[mi][ni] = zero;

  const int srow = wave * 32 + (lane >> 3);
  const int scol = (lane & 7) * 8;
  const bf16* Ag = A + (size_t)(mBase + srow) * K + scol;
  const bf16* Bg = B + (size_t)(nBase + srow) * K + scol;
  bf16* Al = As + srow * 64 + scol;
  bf16* Bl = Bs + srow * 64 + scol;

  for (int kt = 0; kt < K; kt += 64) {
#pragma unroll
    for (int i = 0; i < 4; ++i) {
      gload_lds16(Ag + (size_t)(i * 8) * K + kt, Al + i * 8 * 64);
      gload_lds16(Bg + (size_t)(i * 8) * K + kt, Bl + i * 8 * 64);
    }
    __syncthreads();
#pragma unroll
    for (int kk = 0; kk < 64; kk += 32) {
      bf16x8 af[4], bfr[4];
#pragma unroll
      for (int mi = 0; mi < 4; ++mi)
        af[mi] = *(const bf16x8*)&As[(wm * 64 + mi * 16 + r16) * 64 + kk + quad * 8];
#pragma unroll
      for (int ni = 0; ni < 4; ++ni)
        bfr[ni] = *(const bf16x8*)&Bs[(wn * 64 + ni * 16 + r16) * 64 + kk + quad * 8];
#pragma unroll
      for (int mi = 0; mi < 4; ++mi)
#pragma unroll
        for (int ni = 0; ni < 4; ++ni)
          acc[mi][ni] = __builtin_amdgcn_mfma_f32_16x16x32_bf16(
              af[mi], bfr[ni], acc[mi][ni], 0, 0, 0);
    }
    __syncthreads();
  }

  // epilogue: C row = quad*4 + reg, col = lane&15 (m89/m91-verified layout)
#pragma unroll
  for (int ni = 0; ni < 4; ++ni) {
    const int col = nBase + wn * 64 + ni * 16 + r16;
    const float bv = bias[col];
#pragma unroll
    for (int mi = 0; mi < 4; ++mi) {
      const int row0 = mBase + wm * 64 + mi * 16 + quad * 4;
#pragma unroll
      for (int rr = 0; rr < 4; ++rr) {
        float v = acc[mi][ni][rr] + bv;
        C[(size_t)(row0 + rr) * N + col] = (OutT)v;
      }
    }
  }
}

// ---------------------------------------------------------------------------
// deform: grid (64, 49, 3), block 256.
// Block (n, g, z): lq in [g*4, g*4+4), channels [z*256, z*256+256).
// Thread = one channel ch (head m = ch/192 implicit). 4 unrolled lq chains
// give per-thread ILP; 37632 waves total hide gather latency.
// One atomicAdd per thread into core[n*768 + ch] (49-way per address).
// ---------------------------------------------------------------------------
__global__ void deform_kernel(const float* __restrict__ catout,
                              float* __restrict__ core) {
  const int n   = blockIdx.x;
  const int lq0 = blockIdx.y * 4;
  const int ch  = blockIdx.z * 256 + threadIdx.x;  // 0..767
  const int m   = ch / DH;                          // head
  const float* base = catout + (size_t)n * LQ * NCAT;

  float acc = 0.f;
#pragma unroll
  for (int i = 0; i < 4; ++i) {
    const int lq = lq0 + i;
    const float* row = base + (size_t)lq * NCAT;
    // softmax over the 4 points (wave-mostly-uniform broadcast loads)
    const float l0 = row[800 + m * 4 + 0];
    const float l1 = row[800 + m * 4 + 1];
    const float l2 = row[800 + m * 4 + 2];
    const float l3 = row[800 + m * 4 + 3];
    const float mx = fmaxf(fmaxf(l0, l1), fmaxf(l2, l3));
    const float e0 = __expf(l0 - mx), e1 = __expf(l1 - mx);
    const float e2 = __expf(l2 - mx), e3 = __expf(l3 - mx);
    const float inv = 1.f / (e0 + e1 + e2 + e3);
    const float ew[4] = {e0 * inv, e1 * inv, e2 * inv, e3 * inv};

    const int h = lq / 14, w = lq - (lq / 14) * 14;
    // px = ref_x*14 + off_x - 0.5, ref_x = w/13 (linspace(0,1,14))
    const float px0 = (float)w * (14.f / 13.f) - 0.5f;
    const float py0 = (float)h * (14.f / 13.f) - 0.5f;
#pragma unroll
    for (int p = 0; p < 4; ++p) {
      const float offx = row[768 + (m * 4 + p) * 2 + 0];
      const float offy = row[768 + (m * 4 + p) * 2 + 1];
      const float px = px0 + offx;
      const float py = py0 + offy;
      const float fx = floorf(px), fy = floorf(py);
      const int x0 = (int)fx, y0 = (int)fy;
      const float wx1 = px - fx, wy1 = py - fy;
      const float wx0 = 1.f - wx1, wy0 = 1.f - wy1;
      float sv = 0.f;
      if (y0 >= 0 && y0 < 14) {
        const float* r0 = base + (size_t)(y0 * 14) * NCAT + ch;
        if (x0 >= 0 && x0 < 14)         sv += wx0 * wy0 * r0[(size_t)x0 * NCAT];
        if (x0 + 1 >= 0 && x0 + 1 < 14) sv += wx1 * wy0 * r0[(size_t)(x0 + 1) * NCAT];
      }
      if (y0 + 1 >= 0 && y0 + 1 < 14) {
        const float* r1 = base + (size_t)((y0 + 1) * 14) * NCAT + ch;
        if (x0 >= 0 && x0 < 14)         sv += wx0 * wy1 * r1[(size_t)x0 * NCAT];
        if (x0 + 1 >= 0 && x0 + 1 < 14) sv += wx1 * wy1 * r1[(size_t)(x0 + 1) * NCAT];
      }
      acc += ew[p] * sv;
    }
  }
  atomicAdd(&core[(size_t)n * DM + ch], acc * (1.f / 196.f));
}

// ---------------------------------------------------------------------------
// small_linear: out[n][d] = sum_k in[n][k] * W[d][k] + b[d]
// ---------------------------------------------------------------------------
__global__ void small_linear(const float* __restrict__ in,
                             const float* __restrict__ W,
                             const float* __restrict__ b,
                             float* __restrict__ out) {
  const int n = blockIdx.x;
  const int d = blockIdx.y * 256 + threadIdx.x;
  const float4* a4 = (const float4*)(in + (size_t)n * DM);
  const float4* w4 = (const float4*)(W + (size_t)d * DM);
  float acc = 0.f;
#pragma unroll 4
  for (int k = 0; k < DM / 4; ++k) {
    float4 a = a4[k], w = w4[k];
    acc += a.x * w.x + a.y * w.y + a.z * w.z + a.w * w.w;
  }
  out[(size_t)n * DM + d] = acc + b[d];
}

// ---------------------------------------------------------------------------
extern "C" void kernel_launch(void* const* d_in, const int* in_sizes, int n_in,
                              void* d_out, int out_size, void* d_ws, size_t ws_size,
                              hipStream_t stream) {
  const float* x       = (const float*)d_in[0];
  const float* embed_w = (const float*)d_in[1];
  const float* embed_b = (const float*)d_in[2];
  const float* value_w = (const float*)d_in[3];
  const float* value_b = (const float*)d_in[4];
  const float* off_w   = (const float*)d_in[5];
  const float* off_b   = (const float*)d_in[6];
  const float* aw_w    = (const float*)d_in[7];
  const float* aw_b    = (const float*)d_in[8];
  const float* outp_w  = (const float*)d_in[9];
  const float* outp_b  = (const float*)d_in[10];
  const float* proj_w  = (const float*)d_in[11];
  const float* proj_b  = (const float*)d_in[12];
  float* out = (float*)d_out;

  char* ws = (char*)d_ws;
  bf16*  A      = (bf16*)(ws + OFF_A);
  bf16*  feat   = (bf16*)(ws + OFF_FEAT);
  bf16*  Wemb   = (bf16*)(ws + OFF_WEMB);
  bf16*  Wcat   = (bf16*)(ws + OFF_WCAT);
  float* bcat   = (float*)(ws + OFF_BCAT);
  float* catout = (float*)(ws + OFF_CATO);
  float* core   = (float*)(ws + OFF_CORE);
  float* pooled = (float*)(ws + OFF_POOL);

  prep_kernel<<<dim3(2688), dim3(256), 0, stream>>>(
      embed_w, value_w, off_w, aw_w, value_b, off_b, aw_b, Wemb, Wcat, bcat, core);

  im2col_kernel<<<dim3(2352), dim3(256), 0, stream>>>(x, A);

  gemm_bt<bf16><<<dim3(M_ROWS / 128, DM / 128), dim3(256), 0, stream>>>(
      A, Wemb, embed_b, feat, M_ROWS, DM, DM);

  gemm_bt<float><<<dim3(M_ROWS / 128, NCAT / 128), dim3(256), 0, stream>>>(
      feat, Wcat, bcat, catout, M_ROWS, NCAT, DM);

  deform_kernel<<<dim3(N_IMG, 49, 3), dim3(256), 0, stream>>>(catout, core);

  small_linear<<<dim3(N_IMG, 3), dim3(256), 0, stream>>>(core, outp_w, outp_b, pooled);
  small_linear<<<dim3(N_IMG, 3), dim3(256), 0, stream>>>(pooled, proj_w, proj_b, out);
}

// Round 3
// 248.352 us; speedup vs baseline: 1.3111x; 1.2568x over previous
//
#include <hip/hip_runtime.h>
#include <hip/hip_bf16.h>

// ---------------------------------------------------------------------------
// DeformableSpatialEncoder on MI355X (gfx950)
//
// Pipeline (N=64 images, Lq=196 tokens, D=768, heads=4, Dh=192, points=4):
//   1. prep:    cast embed_w -> bf16 [768,768]; build Wcat bf16 [896,768]
//               (= concat(value_w, off_w, aw_w, zero-pad)); bcat; zero core_mean
//   2. im2col:  x (64,3,224,224) f32 -> A bf16 [12544, 768]  (k = c*256+p*16+q)
//   3. gemm1:   feat_bf16 [12544,768] = A @ Wemb^T + embed_b
//   4. gemm2:   catout f32 [12544,896] = feat @ Wcat^T + bcat
//               cols 0..767 value | 768..799 off | 800..815 aw-logits
//   5. deform:  core_mean[64,768] += mean_lq( softmax(aw) * bilinear(value) )
//               R2: two-phase — LDS-precomputed combined weights + clamped
//               token indices (64 threads), then 64 unconditional pipelined
//               gathers per thread. Kills redundant softmax + branchy loads.
//   6. pooled = core_mean @ outp_w^T + outp_b     (mean commutes with linear!)
//   7. final  = pooled @ proj_w^T + proj_b -> d_out
// ---------------------------------------------------------------------------

using bf16 = __bf16;
typedef bf16  bf16x8 __attribute__((ext_vector_type(8)));
typedef float f32x4  __attribute__((ext_vector_type(4)));

#define N_IMG   64
#define LQ      196
#define DM      768
#define NH      4
#define DH      192
#define NPT     4
#define M_ROWS  (N_IMG * LQ)        // 12544
#define NCAT    896                 // 768 value + 32 off + 16 aw + 80 pad

// ---- workspace layout (bytes, all 256-aligned) ----
#define OFF_A     ((size_t)0)                      // 12544*768*2 = 19267584
#define OFF_FEAT  (OFF_A    + 19267584)            // 19267584
#define OFF_WEMB  (OFF_FEAT + 19267584)            // 768*768*2   = 1179648
#define OFF_WCAT  (OFF_WEMB + 1179648)             // 896*768*2   = 1376256
#define OFF_BCAT  (OFF_WCAT + 1376256)             // 4096
#define OFF_CATO  (OFF_BCAT + 4096)                // 12544*896*4 = 44957696
#define OFF_CORE  (OFF_CATO + 44957696)            // 196608
#define OFF_POOL  (OFF_CORE + 196608)              // 196608

__device__ __forceinline__ void gload_lds16(const bf16* g, bf16* l) {
#if __has_builtin(__builtin_amdgcn_global_load_lds)
  __builtin_amdgcn_global_load_lds(
      (const __attribute__((address_space(1))) void*)g,
      (__attribute__((address_space(3))) void*)l, 16, 0, 0);
#else
  *(bf16x8*)l = *(const bf16x8*)g;
#endif
}

// ---------------------------------------------------------------------------
// prep: weight casts/concat + bias concat + core_mean zero-init
// ---------------------------------------------------------------------------
__global__ void prep_kernel(const float* __restrict__ embed_w,
                            const float* __restrict__ value_w,
                            const float* __restrict__ off_w,
                            const float* __restrict__ aw_w,
                            const float* __restrict__ value_b,
                            const float* __restrict__ off_b,
                            const float* __restrict__ aw_b,
                            bf16* __restrict__ Wemb, bf16* __restrict__ Wcat,
                            float* __restrict__ bcat, float* __restrict__ core) {
  int idx = blockIdx.x * 256 + threadIdx.x;
  if (idx < DM * DM) Wemb[idx] = (bf16)embed_w[idx];
  if (idx < NCAT * DM) {
    int r = idx / DM, k = idx - r * DM;
    float v = 0.f;
    if (r < 768)       v = value_w[idx];
    else if (r < 800)  v = off_w[(r - 768) * DM + k];
    else if (r < 816)  v = aw_w[(r - 800) * DM + k];
    Wcat[idx] = (bf16)v;
  }
  if (idx < NCAT) {
    float v = 0.f;
    if (idx < 768)      v = value_b[idx];
    else if (idx < 800) v = off_b[idx - 768];
    else if (idx < 816) v = aw_b[idx - 800];
    bcat[idx] = v;
  }
  if (idx < N_IMG * DM) core[idx] = 0.f;
}

// ---------------------------------------------------------------------------
// im2col: x[n][c][y][:] -> A[n*196 + (y/16)*14 + w][c*256 + (y%16)*16 + q]
// ---------------------------------------------------------------------------
__global__ void im2col_kernel(const float* __restrict__ x, bf16* __restrict__ A) {
  int t = blockIdx.x * 256 + threadIdx.x;
  if (t >= N_IMG * 3 * 224 * 14) return;
  int w    = t % 14;
  int rest = t / 14;            // (n*3+c)*224 + y
  int y    = rest % 224;
  int nc   = rest / 224;        // n*3 + c
  int c    = nc % 3;
  int n    = nc / 3;
  int h = y >> 4, p = y & 15;
  const float* src = x + (size_t)rest * 224 + w * 16;
  bf16* dst = A + (size_t)(n * LQ + h * 14 + w) * DM + c * 256 + p * 16;
#pragma unroll
  for (int q = 0; q < 16; q += 4) {
    float4 v = *(const float4*)(src + q);
    dst[q + 0] = (bf16)v.x; dst[q + 1] = (bf16)v.y;
    dst[q + 2] = (bf16)v.z; dst[q + 3] = (bf16)v.w;
  }
}

// ---------------------------------------------------------------------------
// gemm_bt: C[M,N] = A[M,K]bf16 @ B[N,K]bf16 ^T + bias[N]
// 128x128 tile, BK=64, 256 threads (4 waves, 2x2), mfma_f32_16x16x32_bf16.
// ---------------------------------------------------------------------------
template <typename OutT>
__global__ void gemm_bt(const bf16* __restrict__ A, const bf16* __restrict__ B,
                        const float* __restrict__ bias, OutT* __restrict__ C,
                        int M, int N, int K) {
  __shared__ bf16 As[128 * 64];
  __shared__ bf16 Bs[128 * 64];

  const int tid  = threadIdx.x;
  const int wave = tid >> 6;
  const int lane = tid & 63;
  const int mBase = blockIdx.x * 128;
  const int nBase = blockIdx.y * 128;
  const int wm = wave & 1;        // wave row (0..1)
  const int wn = wave >> 1;       // wave col (0..1)
  const int quad = lane >> 4;     // 0..3
  const int r16  = lane & 15;

  const f32x4 zero = {0.f, 0.f, 0.f, 0.f};
  f32x4 acc[4][4];
#pragma unroll
  for (int mi = 0; mi < 4; ++mi)
#pragma unroll
    for (int ni = 0; ni < 4; ++ni) acc[mi][ni] = zero;

  const int srow = wave * 32 + (lane >> 3);
  const int scol = (lane & 7) * 8;
  const bf16* Ag = A + (size_t)(mBase + srow) * K + scol;
  const bf16* Bg = B + (size_t)(nBase + srow) * K + scol;
  bf16* Al = As + srow * 64 + scol;
  bf16* Bl = Bs + srow * 64 + scol;

  for (int kt = 0; kt < K; kt += 64) {
#pragma unroll
    for (int i = 0; i < 4; ++i) {
      gload_lds16(Ag + (size_t)(i * 8) * K + kt, Al + i * 8 * 64);
      gload_lds16(Bg + (size_t)(i * 8) * K + kt, Bl + i * 8 * 64);
    }
    __syncthreads();
#pragma unroll
    for (int kk = 0; kk < 64; kk += 32) {
      bf16x8 af[4], bfr[4];
#pragma unroll
      for (int mi = 0; mi < 4; ++mi)
        af[mi] = *(const bf16x8*)&As[(wm * 64 + mi * 16 + r16) * 64 + kk + quad * 8];
#pragma unroll
      for (int ni = 0; ni < 4; ++ni)
        bfr[ni] = *(const bf16x8*)&Bs[(wn * 64 + ni * 16 + r16) * 64 + kk + quad * 8];
#pragma unroll
      for (int mi = 0; mi < 4; ++mi)
#pragma unroll
        for (int ni = 0; ni < 4; ++ni)
          acc[mi][ni] = __builtin_amdgcn_mfma_f32_16x16x32_bf16(
              af[mi], bfr[ni], acc[mi][ni], 0, 0, 0);
    }
    __syncthreads();
  }

  // epilogue: C row = quad*4 + reg, col = lane&15 (m89/m91-verified layout)
#pragma unroll
  for (int ni = 0; ni < 4; ++ni) {
    const int col = nBase + wn * 64 + ni * 16 + r16;
    const float bv = bias[col];
#pragma unroll
    for (int mi = 0; mi < 4; ++mi) {
      const int row0 = mBase + wm * 64 + mi * 16 + quad * 4;
#pragma unroll
      for (int rr = 0; rr < 4; ++rr) {
        float v = acc[mi][ni][rr] + bv;
        C[(size_t)(row0 + rr) * N + col] = (OutT)v;
      }
    }
  }
}

// ---------------------------------------------------------------------------
// deform: grid (64, 49, 3), block 256.
// Phase 1 (64 threads): per (lq_i, head, point) compute 4 combined
//   softmax*bilinear*validity weights + 4 clamped token indices -> LDS.
// Phase 2 (256 threads): thread = channel ch = z*256+tid; 64 unconditional
//   independent gathers weighted from LDS. Every wave is head-uniform
//   (head boundaries 192/384/576 fall on wave edges) -> LDS broadcast.
// ---------------------------------------------------------------------------
__global__ void deform_kernel(const float* __restrict__ catout,
                              float* __restrict__ core) {
  __shared__ float s_w[64][4];
  __shared__ int   s_t[64][4];

  const int n   = blockIdx.x;
  const int lq0 = blockIdx.y * 4;
  const int z   = blockIdx.z;
  const int tid = threadIdx.x;
  const float* base = catout + (size_t)n * LQ * NCAT;

  if (tid < 64) {
    const int i = tid >> 4;          // lq within group
    const int m = (tid >> 2) & 3;    // head
    const int p = tid & 3;           // point
    const int lq = lq0 + i;
    const float* row = base + (size_t)lq * NCAT;

    const float l0 = row[800 + m * 4 + 0];
    const float l1 = row[800 + m * 4 + 1];
    const float l2 = row[800 + m * 4 + 2];
    const float l3 = row[800 + m * 4 + 3];
    const float mx = fmaxf(fmaxf(l0, l1), fmaxf(l2, l3));
    const float e0 = __expf(l0 - mx), e1 = __expf(l1 - mx);
    const float e2 = __expf(l2 - mx), e3 = __expf(l3 - mx);
    const float inv = 1.f / (e0 + e1 + e2 + e3);
    const float ep[4] = {e0, e1, e2, e3};
    const float ew = ep[p] * inv;

    const int h = lq / 14, w = lq - (lq / 14) * 14;
    // px = w*14/13 + offx - 0.5  (ref linspace(0,1,14), normalizer W=14)
    const float px = (float)w * (14.f / 13.f) - 0.5f + row[768 + (m * 4 + p) * 2 + 0];
    const float py = (float)h * (14.f / 13.f) - 0.5f + row[768 + (m * 4 + p) * 2 + 1];
    const float fx = floorf(px), fy = floorf(py);
    const int x0 = (int)fx, y0 = (int)fy;
    const float wx1 = px - fx, wy1 = py - fy;
    const float wx0 = 1.f - wx1, wy0 = 1.f - wy1;

    const bool vx0 = (x0 >= 0) & (x0 < 14);
    const bool vx1 = (x0 >= -1) & (x0 < 13);
    const bool vy0 = (y0 >= 0) & (y0 < 14);
    const bool vy1 = (y0 >= -1) & (y0 < 13);
    const int cx0 = min(max(x0, 0), 13),     cx1 = min(max(x0 + 1, 0), 13);
    const int cy0 = min(max(y0, 0), 13) * 14, cy1 = min(max(y0 + 1, 0), 13) * 14;

    s_w[tid][0] = (vx0 & vy0) ? ew * wx0 * wy0 : 0.f;
    s_w[tid][1] = (vx1 & vy0) ? ew * wx1 * wy0 : 0.f;
    s_w[tid][2] = (vx0 & vy1) ? ew * wx0 * wy1 : 0.f;
    s_w[tid][3] = (vx1 & vy1) ? ew * wx1 * wy1 : 0.f;
    s_t[tid][0] = cy0 + cx0;
    s_t[tid][1] = cy0 + cx1;
    s_t[tid][2] = cy1 + cx0;
    s_t[tid][3] = cy1 + cx1;
  }
  __syncthreads();

  const int ch = z * 256 + tid;     // 0..767 (value column)
  const int m  = ch / DH;           // head (wave-uniform)
  float acc = 0.f;
#pragma unroll
  for (int i = 0; i < 4; ++i) {
#pragma unroll
    for (int p = 0; p < 4; ++p) {
      const int e = i * 16 + m * 4 + p;
      const float4 w4 = *(const float4*)s_w[e];
      const int4   t4 = *(const int4*)s_t[e];
      acc += w4.x * base[(size_t)(t4.x * NCAT + ch)];
      acc += w4.y * base[(size_t)(t4.y * NCAT + ch)];
      acc += w4.z * base[(size_t)(t4.z * NCAT + ch)];
      acc += w4.w * base[(size_t)(t4.w * NCAT + ch)];
    }
  }
  atomicAdd(&core[(size_t)n * DM + ch], acc * (1.f / 196.f));
}

// ---------------------------------------------------------------------------
// small_linear: out[n][d] = sum_k in[n][k] * W[d][k] + b[d]
// ---------------------------------------------------------------------------
__global__ void small_linear(const float* __restrict__ in,
                             const float* __restrict__ W,
                             const float* __restrict__ b,
                             float* __restrict__ out) {
  const int n = blockIdx.x;
  const int d = blockIdx.y * 256 + threadIdx.x;
  const float4* a4 = (const float4*)(in + (size_t)n * DM);
  const float4* w4 = (const float4*)(W + (size_t)d * DM);
  float acc = 0.f;
#pragma unroll 4
  for (int k = 0; k < DM / 4; ++k) {
    float4 a = a4[k], w = w4[k];
    acc += a.x * w.x + a.y * w.y + a.z * w.z + a.w * w.w;
  }
  out[(size_t)n * DM + d] = acc + b[d];
}

// ---------------------------------------------------------------------------
extern "C" void kernel_launch(void* const* d_in, const int* in_sizes, int n_in,
                              void* d_out, int out_size, void* d_ws, size_t ws_size,
                              hipStream_t stream) {
  const float* x       = (const float*)d_in[0];
  const float* embed_w = (const float*)d_in[1];
  const float* embed_b = (const float*)d_in[2];
  const float* value_w = (const float*)d_in[3];
  const float* value_b = (const float*)d_in[4];
  const float* off_w   = (const float*)d_in[5];
  const float* off_b   = (const float*)d_in[6];
  const float* aw_w    = (const float*)d_in[7];
  const float* aw_b    = (const float*)d_in[8];
  const float* outp_w  = (const float*)d_in[9];
  const float* outp_b  = (const float*)d_in[10];
  const float* proj_w  = (const float*)d_in[11];
  const float* proj_b  = (const float*)d_in[12];
  float* out = (float*)d_out;

  char* ws = (char*)d_ws;
  bf16*  A      = (bf16*)(ws + OFF_A);
  bf16*  feat   = (bf16*)(ws + OFF_FEAT);
  bf16*  Wemb   = (bf16*)(ws + OFF_WEMB);
  bf16*  Wcat   = (bf16*)(ws + OFF_WCAT);
  float* bcat   = (float*)(ws + OFF_BCAT);
  float* catout = (float*)(ws + OFF_CATO);
  float* core   = (float*)(ws + OFF_CORE);
  float* pooled = (float*)(ws + OFF_POOL);

  prep_kernel<<<dim3(2688), dim3(256), 0, stream>>>(
      embed_w, value_w, off_w, aw_w, value_b, off_b, aw_b, Wemb, Wcat, bcat, core);

  im2col_kernel<<<dim3(2352), dim3(256), 0, stream>>>(x, A);

  gemm_bt<bf16><<<dim3(M_ROWS / 128, DM / 128), dim3(256), 0, stream>>>(
      A, Wemb, embed_b, feat, M_ROWS, DM, DM);

  gemm_bt<float><<<dim3(M_ROWS / 128, NCAT / 128), dim3(256), 0, stream>>>(
      feat, Wcat, bcat, catout, M_ROWS, NCAT, DM);

  deform_kernel<<<dim3(N_IMG, 49, 3), dim3(256), 0, stream>>>(catout, core);

  small_linear<<<dim3(N_IMG, 3), dim3(256), 0, stream>>>(core, outp_w, outp_b, pooled);
  small_linear<<<dim3(N_IMG, 3), dim3(256), 0, stream>>>(pooled, proj_w, proj_b, out);
}

// Round 4
// 236.183 us; speedup vs baseline: 1.3786x; 1.0515x over previous
//
#include <hip/hip_runtime.h>
#include <hip/hip_bf16.h>

// ---------------------------------------------------------------------------
// DeformableSpatialEncoder on MI355X (gfx950)
//
// Pipeline (N=64 images, Lq=196 tokens, D=768, heads=4, Dh=192, points=4):
//   1. stage:   [merged] im2col x->A bf16 [12544,768] (coalesced writes) +
//               weight casts (Wemb, Wcat bf16) + bcat + core zero
//   2. gemm1:   feat_bf16 [12544,768] = A @ Wemb^T + embed_b   (N-tile-fast grid)
//   3. gemm2:   mixed epilogue: value -> Vbuf bf16 [12544,768],
//               off/aw logits -> OA f32 [12544,64] (cols 0..31 off, 32..47 aw)
//   4. deform:  core_mean[64,768] += mean_lq( softmax(aw) * bilinear(value) )
//               two-phase: LDS weights/indices, then 64 unconditional bf16
//               gathers per thread.
//   5. pooled = core_mean @ outp_w^T + outp_b   (mean commutes with linear)
//   6. final  = pooled @ proj_w^T + proj_b -> d_out
// ---------------------------------------------------------------------------

using bf16 = __bf16;
typedef bf16  bf16x8 __attribute__((ext_vector_type(8)));
typedef float f32x4  __attribute__((ext_vector_type(4)));

#define N_IMG   64
#define LQ      196
#define DM      768
#define NH      4
#define DH      192
#define M_ROWS  (N_IMG * LQ)        // 12544
#define NCAT    896                 // 768 value + 32 off + 16 aw + 80 pad

// ---- workspace layout (bytes, all 256-aligned) ----
#define OFF_A     ((size_t)0)                      // 12544*768*2 = 19267584
#define OFF_FEAT  (OFF_A    + 19267584)            // 19267584
#define OFF_WEMB  (OFF_FEAT + 19267584)            // 768*768*2   = 1179648
#define OFF_WCAT  (OFF_WEMB + 1179648)             // 896*768*2   = 1376256
#define OFF_BCAT  (OFF_WCAT + 1376256)             // 4096
#define OFF_VBUF  (OFF_BCAT + 4096)                // 12544*768*2 = 19267584
#define OFF_OA    (OFF_VBUF + 19267584)            // 12544*64*4  = 3211264
#define OFF_CORE  (OFF_OA   + 3211264)             // 196608
#define OFF_POOL  (OFF_CORE + 196608)              // 196608

__device__ __forceinline__ void gload_lds16(const bf16* g, bf16* l) {
#if __has_builtin(__builtin_amdgcn_global_load_lds)
  __builtin_amdgcn_global_load_lds(
      (const __attribute__((address_space(1))) void*)g,
      (__attribute__((address_space(3))) void*)l, 16, 0, 0);
#else
  *(bf16x8*)l = *(const bf16x8*)g;
#endif
}

// ---------------------------------------------------------------------------
// stage: blocks [0,9408)  -> im2col, one thread = 4 consecutive k of one row
//        blocks [9408,12096) -> weight prep (cast/concat) + core zero
// im2col: A[row][k], row=n*196+h*14+w, k=c*256+p*16+q
//   writes: consecutive threads -> consecutive 8B  (fully coalesced)
//   reads:  float4; 4 lanes cover one 64B segment of an image row
// ---------------------------------------------------------------------------
__global__ void stage_kernel(const float* __restrict__ x,
                             const float* __restrict__ embed_w,
                             const float* __restrict__ value_w,
                             const float* __restrict__ off_w,
                             const float* __restrict__ aw_w,
                             const float* __restrict__ value_b,
                             const float* __restrict__ off_b,
                             const float* __restrict__ aw_b,
                             bf16* __restrict__ A,
                             bf16* __restrict__ Wemb, bf16* __restrict__ Wcat,
                             float* __restrict__ bcat, float* __restrict__ core) {
  const int bid = blockIdx.x;
  if (bid < 9408) {                       // ---- im2col ----
    const int t   = bid * 256 + threadIdx.x;   // < 12544*192 exactly
    const int row = t / 192;
    const int j   = t - row * 192;
    const int k   = j * 4;                // k = c*256 + p*16 + q, q%4==0
    const int c   = k >> 8;
    const int r   = k & 255;
    const int p   = r >> 4;
    const int q   = r & 15;
    const int n   = row / 196;
    const int lq  = row - n * 196;
    const int h   = lq / 14;
    const int w   = lq - h * 14;
    const float4 v = *(const float4*)(x +
        ((((size_t)n * 3 + c) * 224) + h * 16 + p) * 224 + w * 16 + q);
    bf16* dst = A + (size_t)row * DM + k;
    dst[0] = (bf16)v.x; dst[1] = (bf16)v.y; dst[2] = (bf16)v.z; dst[3] = (bf16)v.w;
    return;
  }
  // ---- prep ----
  const int idx = (bid - 9408) * 256 + threadIdx.x;   // < 688128 exactly
  if (idx < DM * DM) Wemb[idx] = (bf16)embed_w[idx];
  {
    int rr = idx / DM, kk = idx - rr * DM;
    float v = 0.f;
    if (rr < 768)       v = value_w[idx];
    else if (rr < 800)  v = off_w[(rr - 768) * DM + kk];
    else if (rr < 816)  v = aw_w[(rr - 800) * DM + kk];
    Wcat[idx] = (bf16)v;
  }
  if (idx < NCAT) {
    float v = 0.f;
    if (idx < 768)      v = value_b[idx];
    else if (idx < 800) v = off_b[idx - 768];
    else if (idx < 816) v = aw_b[idx - 800];
    bcat[idx] = v;
  }
  if (idx < N_IMG * DM) core[idx] = 0.f;
}

// ---------------------------------------------------------------------------
// gemm_bt: C[M,N] = A[M,K]bf16 @ B[N,K]bf16 ^T + bias[N]
// 128x128 tile, BK=64, 256 threads (4 waves, 2x2), mfma_f32_16x16x32_bf16.
// grid = (N/128, M/128): N-tile FAST so consecutive blocks reuse one A-tile
// and B stays L2-resident (B is small for our shapes).
// ---------------------------------------------------------------------------
template <typename OutT>
__global__ void gemm_bt(const bf16* __restrict__ A, const bf16* __restrict__ B,
                        const float* __restrict__ bias, OutT* __restrict__ C,
                        int M, int N, int K) {
  __shared__ bf16 As[128 * 64];
  __shared__ bf16 Bs[128 * 64];

  const int tid  = threadIdx.x;
  const int wave = tid >> 6;
  const int lane = tid & 63;
  const int nBase = blockIdx.x * 128;
  const int mBase = blockIdx.y * 128;
  const int wm = wave & 1;
  const int wn = wave >> 1;
  const int quad = lane >> 4;
  const int r16  = lane & 15;

  const f32x4 zero = {0.f, 0.f, 0.f, 0.f};
  f32x4 acc[4][4];
#pragma unroll
  for (int mi = 0; mi < 4; ++mi)
#pragma unroll
    for (int ni = 0; ni < 4; ++ni) acc[mi][ni] = zero;

  const int srow = wave * 32 + (lane >> 3);
  const int scol = (lane & 7) * 8;
  const bf16* Ag = A + (size_t)(mBase + srow) * K + scol;
  const bf16* Bg = B + (size_t)(nBase + srow) * K + scol;
  bf16* Al = As + srow * 64 + scol;
  bf16* Bl = Bs + srow * 64 + scol;

  for (int kt = 0; kt < K; kt += 64) {
#pragma unroll
    for (int i = 0; i < 4; ++i) {
      gload_lds16(Ag + (size_t)(i * 8) * K + kt, Al + i * 8 * 64);
      gload_lds16(Bg + (size_t)(i * 8) * K + kt, Bl + i * 8 * 64);
    }
    __syncthreads();
#pragma unroll
    for (int kk = 0; kk < 64; kk += 32) {
      bf16x8 af[4], bfr[4];
#pragma unroll
      for (int mi = 0; mi < 4; ++mi)
        af[mi] = *(const bf16x8*)&As[(wm * 64 + mi * 16 + r16) * 64 + kk + quad * 8];
#pragma unroll
      for (int ni = 0; ni < 4; ++ni)
        bfr[ni] = *(const bf16x8*)&Bs[(wn * 64 + ni * 16 + r16) * 64 + kk + quad * 8];
#pragma unroll
      for (int mi = 0; mi < 4; ++mi)
#pragma unroll
        for (int ni = 0; ni < 4; ++ni)
          acc[mi][ni] = __builtin_amdgcn_mfma_f32_16x16x32_bf16(
              af[mi], bfr[ni], acc[mi][ni], 0, 0, 0);
    }
    __syncthreads();
  }

  // epilogue: C row = quad*4 + reg, col = lane&15 (m89/m91-verified layout)
#pragma unroll
  for (int ni = 0; ni < 4; ++ni) {
    const int col = nBase + wn * 64 + ni * 16 + r16;
    const float bv = bias[col];
#pragma unroll
    for (int mi = 0; mi < 4; ++mi) {
      const int row0 = mBase + wm * 64 + mi * 16 + quad * 4;
#pragma unroll
      for (int rr = 0; rr < 4; ++rr) {
        float v = acc[mi][ni][rr] + bv;
        C[(size_t)(row0 + rr) * N + col] = (OutT)v;
      }
    }
  }
}

// ---------------------------------------------------------------------------
// gemm2_mixed: same K-loop; epilogue splits columns:
//   col <  768 -> Vbuf bf16 [M,768]
//   col <  816 -> OA   f32  [M,64]  at col-768 (0..31 off, 32..47 aw)
//   col >= 816 -> dropped (zero-pad columns)
// ---------------------------------------------------------------------------
__global__ void gemm2_mixed(const bf16* __restrict__ A, const bf16* __restrict__ B,
                            const float* __restrict__ bias,
                            bf16* __restrict__ Vb, float* __restrict__ OA,
                            int M, int N, int K) {
  __shared__ bf16 As[128 * 64];
  __shared__ bf16 Bs[128 * 64];

  const int tid  = threadIdx.x;
  const int wave = tid >> 6;
  const int lane = tid & 63;
  const int nBase = blockIdx.x * 128;
  const int mBase = blockIdx.y * 128;
  const int wm = wave & 1;
  const int wn = wave >> 1;
  const int quad = lane >> 4;
  const int r16  = lane & 15;

  const f32x4 zero = {0.f, 0.f, 0.f, 0.f};
  f32x4 acc[4][4];
#pragma unroll
  for (int mi = 0; mi < 4; ++mi)
#pragma unroll
    for (int ni = 0; ni < 4; ++ni) acc[mi][ni] = zero;

  const int srow = wave * 32 + (lane >> 3);
  const int scol = (lane & 7) * 8;
  const bf16* Ag = A + (size_t)(mBase + srow) * K + scol;
  const bf16* Bg = B + (size_t)(nBase + srow) * K + scol;
  bf16* Al = As + srow * 64 + scol;
  bf16* Bl = Bs + srow * 64 + scol;

  for (int kt = 0; kt < K; kt += 64) {
#pragma unroll
    for (int i = 0; i < 4; ++i) {
      gload_lds16(Ag + (size_t)(i * 8) * K + kt, Al + i * 8 * 64);
      gload_lds16(Bg + (size_t)(i * 8) * K + kt, Bl + i * 8 * 64);
    }
    __syncthreads();
#pragma unroll
    for (int kk = 0; kk < 64; kk += 32) {
      bf16x8 af[4], bfr[4];
#pragma unroll
      for (int mi = 0; mi < 4; ++mi)
        af[mi] = *(const bf16x8*)&As[(wm * 64 + mi * 16 + r16) * 64 + kk + quad * 8];
#pragma unroll
      for (int ni = 0; ni < 4; ++ni)
        bfr[ni] = *(const bf16x8*)&Bs[(wn * 64 + ni * 16 + r16) * 64 + kk + quad * 8];
#pragma unroll
      for (int mi = 0; mi < 4; ++mi)
#pragma unroll
        for (int ni = 0; ni < 4; ++ni)
          acc[mi][ni] = __builtin_amdgcn_mfma_f32_16x16x32_bf16(
              af[mi], bfr[ni], acc[mi][ni], 0, 0, 0);
    }
    __syncthreads();
  }

#pragma unroll
  for (int ni = 0; ni < 4; ++ni) {
    const int col = nBase + wn * 64 + ni * 16 + r16;
    const float bv = bias[col];
#pragma unroll
    for (int mi = 0; mi < 4; ++mi) {
      const int row0 = mBase + wm * 64 + mi * 16 + quad * 4;
#pragma unroll
      for (int rr = 0; rr < 4; ++rr) {
        float v = acc[mi][ni][rr] + bv;
        int row = row0 + rr;
        if (col < 768) {
          Vb[(size_t)row * 768 + col] = (bf16)v;
        } else if (col < 816) {
          OA[(size_t)row * 64 + (col - 768)] = v;
        }
      }
    }
  }
}

// ---------------------------------------------------------------------------
// deform: grid (64, 49, 3), block 256.
// Phase 1 (64 threads): per (lq_i, head, point) compute 4 combined
//   softmax*bilinear*validity weights + 4 clamped token indices -> LDS.
//   Reads off/aw from OA f32 [12544,64].
// Phase 2 (256 threads): thread = channel; 64 unconditional bf16 gathers
//   from Vbuf, weights broadcast from LDS (waves are head-uniform).
// ---------------------------------------------------------------------------
__global__ void deform_kernel(const bf16* __restrict__ Vb,
                              const float* __restrict__ OA,
                              float* __restrict__ core) {
  __shared__ float s_w[64][4];
  __shared__ int   s_t[64][4];

  const int n   = blockIdx.x;
  const int lq0 = blockIdx.y * 4;
  const int z   = blockIdx.z;
  const int tid = threadIdx.x;

  if (tid < 64) {
    const int i = tid >> 4;          // lq within group
    const int m = (tid >> 2) & 3;    // head
    const int p = tid & 3;           // point
    const int lq = lq0 + i;
    const float* row = OA + ((size_t)n * LQ + lq) * 64;

    const float l0 = row[32 + m * 4 + 0];
    const float l1 = row[32 + m * 4 + 1];
    const float l2 = row[32 + m * 4 + 2];
    const float l3 = row[32 + m * 4 + 3];
    const float mx = fmaxf(fmaxf(l0, l1), fmaxf(l2, l3));
    const float e0 = __expf(l0 - mx), e1 = __expf(l1 - mx);
    const float e2 = __expf(l2 - mx), e3 = __expf(l3 - mx);
    const float inv = 1.f / (e0 + e1 + e2 + e3);
    const float ep[4] = {e0, e1, e2, e3};
    const float ew = ep[p] * inv;

    const int h = lq / 14, w = lq - (lq / 14) * 14;
    // px = w*14/13 + offx - 0.5  (ref linspace(0,1,14), normalizer W=14)
    const float px = (float)w * (14.f / 13.f) - 0.5f + row[(m * 4 + p) * 2 + 0];
    const float py = (float)h * (14.f / 13.f) - 0.5f + row[(m * 4 + p) * 2 + 1];
    const float fx = floorf(px), fy = floorf(py);
    const int x0 = (int)fx, y0 = (int)fy;
    const float wx1 = px - fx, wy1 = py - fy;
    const float wx0 = 1.f - wx1, wy0 = 1.f - wy1;

    const bool vx0 = (x0 >= 0) & (x0 < 14);
    const bool vx1 = (x0 >= -1) & (x0 < 13);
    const bool vy0 = (y0 >= 0) & (y0 < 14);
    const bool vy1 = (y0 >= -1) & (y0 < 13);
    const int cx0 = min(max(x0, 0), 13),      cx1 = min(max(x0 + 1, 0), 13);
    const int cy0 = min(max(y0, 0), 13) * 14, cy1 = min(max(y0 + 1, 0), 13) * 14;

    s_w[tid][0] = (vx0 & vy0) ? ew * wx0 * wy0 : 0.f;
    s_w[tid][1] = (vx1 & vy0) ? ew * wx1 * wy0 : 0.f;
    s_w[tid][2] = (vx0 & vy1) ? ew * wx0 * wy1 : 0.f;
    s_w[tid][3] = (vx1 & vy1) ? ew * wx1 * wy1 : 0.f;
    s_t[tid][0] = cy0 + cx0;
    s_t[tid][1] = cy0 + cx1;
    s_t[tid][2] = cy1 + cx0;
    s_t[tid][3] = cy1 + cx1;
  }
  __syncthreads();

  const int ch = z * 256 + tid;     // 0..767 (value column)
  const int m  = ch / DH;           // head (wave-uniform)
  const bf16* vb = Vb + (size_t)n * LQ * 768 + ch;
  float acc = 0.f;
#pragma unroll
  for (int i = 0; i < 4; ++i) {
#pragma unroll
    for (int p = 0; p < 4; ++p) {
      const int e = i * 16 + m * 4 + p;
      const float4 w4 = *(const float4*)s_w[e];
      const int4   t4 = *(const int4*)s_t[e];
      acc += w4.x * (float)vb[(size_t)t4.x * 768];
      acc += w4.y * (float)vb[(size_t)t4.y * 768];
      acc += w4.z * (float)vb[(size_t)t4.z * 768];
      acc += w4.w * (float)vb[(size_t)t4.w * 768];
    }
  }
  atomicAdd(&core[(size_t)n * DM + ch], acc * (1.f / 196.f));
}

// ---------------------------------------------------------------------------
// small_linear: out[n][d] = sum_k in[n][k] * W[d][k] + b[d]
// ---------------------------------------------------------------------------
__global__ void small_linear(const float* __restrict__ in,
                             const float* __restrict__ W,
                             const float* __restrict__ b,
                             float* __restrict__ out) {
  const int n = blockIdx.x;
  const int d = blockIdx.y * 256 + threadIdx.x;
  const float4* a4 = (const float4*)(in + (size_t)n * DM);
  const float4* w4 = (const float4*)(W + (size_t)d * DM);
  float acc = 0.f;
#pragma unroll 4
  for (int k = 0; k < DM / 4; ++k) {
    float4 a = a4[k], w = w4[k];
    acc += a.x * w.x + a.y * w.y + a.z * w.z + a.w * w.w;
  }
  out[(size_t)n * DM + d] = acc + b[d];
}

// ---------------------------------------------------------------------------
extern "C" void kernel_launch(void* const* d_in, const int* in_sizes, int n_in,
                              void* d_out, int out_size, void* d_ws, size_t ws_size,
                              hipStream_t stream) {
  const float* x       = (const float*)d_in[0];
  const float* embed_w = (const float*)d_in[1];
  const float* embed_b = (const float*)d_in[2];
  const float* value_w = (const float*)d_in[3];
  const float* value_b = (const float*)d_in[4];
  const float* off_w   = (const float*)d_in[5];
  const float* off_b   = (const float*)d_in[6];
  const float* aw_w    = (const float*)d_in[7];
  const float* aw_b    = (const float*)d_in[8];
  const float* outp_w  = (const float*)d_in[9];
  const float* outp_b  = (const float*)d_in[10];
  const float* proj_w  = (const float*)d_in[11];
  const float* proj_b  = (const float*)d_in[12];
  float* out = (float*)d_out;

  char* ws = (char*)d_ws;
  bf16*  A      = (bf16*)(ws + OFF_A);
  bf16*  feat   = (bf16*)(ws + OFF_FEAT);
  bf16*  Wemb   = (bf16*)(ws + OFF_WEMB);
  bf16*  Wcat   = (bf16*)(ws + OFF_WCAT);
  float* bcat   = (float*)(ws + OFF_BCAT);
  bf16*  Vbuf   = (bf16*)(ws + OFF_VBUF);
  float* OA     = (float*)(ws + OFF_OA);
  float* core   = (float*)(ws + OFF_CORE);
  float* pooled = (float*)(ws + OFF_POOL);

  stage_kernel<<<dim3(12096), dim3(256), 0, stream>>>(
      x, embed_w, value_w, off_w, aw_w, value_b, off_b, aw_b,
      A, Wemb, Wcat, bcat, core);

  gemm_bt<bf16><<<dim3(DM / 128, M_ROWS / 128), dim3(256), 0, stream>>>(
      A, Wemb, embed_b, feat, M_ROWS, DM, DM);

  gemm2_mixed<<<dim3(NCAT / 128, M_ROWS / 128), dim3(256), 0, stream>>>(
      feat, Wcat, bcat, Vbuf, OA, M_ROWS, NCAT, DM);

  deform_kernel<<<dim3(N_IMG, 49, 3), dim3(256), 0, stream>>>(Vbuf, OA, core);

  small_linear<<<dim3(N_IMG, 3), dim3(256), 0, stream>>>(core, outp_w, outp_b, pooled);
  small_linear<<<dim3(N_IMG, 3), dim3(256), 0, stream>>>(pooled, proj_w, proj_b, out);
}